// Round 4
// baseline (846.805 us; speedup 1.0000x reference)
//
#include <hip/hip_runtime.h>

#define E_EDGES 500000
#define N_NODES 30000
#define H_DIM   256
#define SPLIT_N 14976                 // node split, multiple of 64
#define SCAT_BLOCKS 489               // ceil((E/4)/256)

typedef float  floatx4 __attribute__((ext_vector_type(4)));
typedef float  floatx2 __attribute__((ext_vector_type(2)));
typedef short  shortx4 __attribute__((ext_vector_type(4)));
typedef short  shortx8 __attribute__((ext_vector_type(8)));
typedef __bf16 bf16x8  __attribute__((ext_vector_type(8)));

__device__ inline short f2bf(float f) {
    unsigned u = __builtin_bit_cast(unsigned, f);
    u += 0x7fffu + ((u >> 16) & 1u);        // round-to-nearest-even
    return (short)(u >> 16);
}
__device__ inline float bf2f(short s) {
    unsigned u = ((unsigned)(unsigned short)s) << 16;
    return __builtin_bit_cast(float, u);
}

// ---------------------------------------------------------------------------
// Fused: blocks [0,256) reformat W_up/W_hidden into MFMA B-fragment bf16;
// blocks [256,745) histogram edge target ids (int4 reads).
// ---------------------------------------------------------------------------
__global__ __launch_bounds__(256) void prep_hist(
    const float* __restrict__ wup, const float* __restrict__ whid,
    short* __restrict__ wfrag,
    const int* __restrict__ idx, int* __restrict__ counts)
{
    const int b = blockIdx.x;
    if (b < 256) {
        int g   = b * 256 + threadIdx.x;        // 0..65535
        int mat = g >> 13;
        int grp = g & 8191;
        int a = mat >> 2, lay = mat & 3;
        const float* src = (lay == 0) ? (wup + a * 65536)
                                      : (whid + (a * 3 + lay - 1) * 65536);
        int ks  = grp >> 10;
        int rem = grp & 1023;
        int ntg = rem >> 6;
        int lane = rem & 63;
        int q = lane >> 4, c = lane & 15;
        int col = ntg * 16 + c;
        int k0  = ks * 32 + q * 8;
        shortx8 v;
#pragma unroll
        for (int j = 0; j < 8; j++) v[j] = f2bf(src[(k0 + j) * 256 + col]);
        ((shortx8*)wfrag)[g] = v;
    } else {
        int g = (b - 256) * 256 + threadIdx.x;  // one int4 = 4 edges
        if (g < E_EDGES / 4) {
            int4 v = ((const int4*)idx)[g];
            atomicAdd(&counts[v.x], 1);
            atomicAdd(&counts[v.y], 1);
            atomicAdd(&counts[v.z], 1);
            atomicAdd(&counts[v.w], 1);
        }
    }
}

// ---------------------------------------------------------------------------
// Exclusive scan: chunk 32/thread with int4 loads (shorter latency chain).
// ---------------------------------------------------------------------------
__global__ __launch_bounds__(1024) void scan_kernel(
    const int* __restrict__ counts, int* __restrict__ offsets,
    int* __restrict__ cursor)
{
    const int t = threadIdx.x;
    const int lane = t & 63, wave = t >> 6;
    const int base = t * 32;
    int local[32];
    int s = 0;
    if (base < N_NODES) {
#pragma unroll
        for (int q4 = 0; q4 < 8; q4++) {
            int4 v = ((const int4*)counts)[t * 8 + q4];
            int i0 = base + q4 * 4;
            int c0 = (i0 + 0 < N_NODES) ? v.x : 0;
            int c1 = (i0 + 1 < N_NODES) ? v.y : 0;
            int c2 = (i0 + 2 < N_NODES) ? v.z : 0;
            int c3 = (i0 + 3 < N_NODES) ? v.w : 0;
            local[i0 - base + 0] = s; s += c0;
            local[i0 - base + 1] = s; s += c1;
            local[i0 - base + 2] = s; s += c2;
            local[i0 - base + 3] = s; s += c3;
        }
    } else {
#pragma unroll
        for (int j = 0; j < 32; j++) local[j] = 0;
    }
    int incl = s;
#pragma unroll
    for (int d = 1; d < 64; d <<= 1) {
        int v = __shfl_up(incl, d);
        if (lane >= d) incl += v;
    }
    __shared__ int part[16];
    if (lane == 63) part[wave] = incl;
    __syncthreads();
    if (t == 0) {
        int run = 0;
#pragma unroll
        for (int k = 0; k < 16; k++) { int v = part[k]; part[k] = run; run += v; }
    }
    __syncthreads();
    int excl = part[wave] + incl - s;
#pragma unroll
    for (int j = 0; j < 32; j++) {
        int n = base + j;
        if (n < N_NODES) { int o = excl + local[j]; offsets[n] = o; cursor[n] = o; }
    }
    if (t == 0) offsets[N_NODES] = E_EDGES;
}

// ---------------------------------------------------------------------------
// Scatter pass for a node range [lo,hi): int4 idx reads, shared cursor.
// ---------------------------------------------------------------------------
__device__ inline void scatter_body(
    int g, const int* __restrict__ idx, int* __restrict__ cursor,
    int* __restrict__ edge_list, int lo, int hi)
{
    if (g >= E_EDGES / 4) return;
    int4 v = ((const int4*)idx)[g];
    int e0 = g * 4;
    if (v.x >= lo && v.x < hi) { int p = atomicAdd(&cursor[v.x], 1); edge_list[p] = e0 + 0; }
    if (v.y >= lo && v.y < hi) { int p = atomicAdd(&cursor[v.y], 1); edge_list[p] = e0 + 1; }
    if (v.z >= lo && v.z < hi) { int p = atomicAdd(&cursor[v.z], 1); edge_list[p] = e0 + 2; }
    if (v.w >= lo && v.w < hi) { int p = atomicAdd(&cursor[v.w], 1); edge_list[p] = e0 + 3; }
}

__global__ __launch_bounds__(256) void scatter_lo(
    const int* __restrict__ idx, int* __restrict__ cursor,
    int* __restrict__ edge_list)
{
    scatter_body(blockIdx.x * 256 + threadIdx.x, idx, cursor, edge_list, 0, SPLIT_N);
}

// ---------------------------------------------------------------------------
// Gather body: one wave per node in [node_base, node_base+node_cnt).
// ---------------------------------------------------------------------------
__device__ inline void gather_body(
    int blk, int tid,
    const float* __restrict__ x, const float* __restrict__ rbf,
    const int* __restrict__ edge_list, const int* __restrict__ offsets,
    const float* __restrict__ wrbf, short* __restrict__ h16,
    int node_base, int node_cnt)
{
    int node = node_base + blk * 4 + (tid >> 6);
    if (node >= node_base + node_cnt || node >= N_NODES) return;
    int lane = tid & 63;

    const floatx4* wr4 = (const floatx4*)wrbf;   // [6][64] float4
    floatx4 wr[6];
#pragma unroll
    for (int k = 0; k < 6; k++) wr[k] = wr4[k * 64 + lane];

    int beg = offsets[node], end = offsets[node + 1];
    floatx4 acc = {0.f, 0.f, 0.f, 0.f};
    for (int j0 = beg; j0 < end; j0 += 64) {
        int myid = (j0 + lane < end)
                 ? __builtin_nontemporal_load(&edge_list[j0 + lane]) : 0;
        int cnt  = end - j0; if (cnt > 64) cnt = 64;
#pragma unroll 2
        for (int g = 0; g < cnt; g++) {
            int e = __shfl(myid, g);
            const float* rp = rbf + e * 6;
            floatx2 r01 = __builtin_nontemporal_load((const floatx2*)(rp + 0));
            floatx2 r23 = __builtin_nontemporal_load((const floatx2*)(rp + 2));
            floatx2 r45 = __builtin_nontemporal_load((const floatx2*)(rp + 4));
            floatx4 xv = __builtin_nontemporal_load(
                &((const floatx4*)x)[(size_t)e * 64 + lane]);
            floatx4 p = r01[0] * wr[0] + r01[1] * wr[1] + r23[0] * wr[2]
                      + r23[1] * wr[3] + r45[0] * wr[4] + r45[1] * wr[5];
            acc += p * xv;
        }
    }
    shortx4 s4 = { f2bf(acc.x), f2bf(acc.y), f2bf(acc.z), f2bf(acc.w) };
    ((shortx4*)h16)[(size_t)node * 64 + lane] = s4;
}

// D4: blocks [0,SCAT_BLOCKS) scatter high-node edges; rest gather low nodes.
// Disjoint cursor/edge_list entries -> no race with concurrent gatherA.
__global__ __launch_bounds__(256) void scatterB_gatherA(
    const int* __restrict__ idx, int* __restrict__ cursor,
    int* __restrict__ edge_list,
    const float* __restrict__ x, const float* __restrict__ rbf,
    const int* __restrict__ offsets, const float* __restrict__ wrbf,
    short* __restrict__ h16)
{
    if (blockIdx.x < SCAT_BLOCKS) {
        scatter_body(blockIdx.x * 256 + threadIdx.x, idx, cursor, edge_list,
                     SPLIT_N, N_NODES);
    } else {
        gather_body(blockIdx.x - SCAT_BLOCKS, threadIdx.x,
                    x, rbf, edge_list, offsets, wrbf, h16, 0, SPLIT_N);
    }
}

__global__ __launch_bounds__(256) void gather_hi(
    const float* __restrict__ x, const float* __restrict__ rbf,
    const int* __restrict__ edge_list, const int* __restrict__ offsets,
    const float* __restrict__ wrbf, short* __restrict__ h16)
{
    gather_body(blockIdx.x, threadIdx.x, x, rbf, edge_list, offsets, wrbf, h16,
                SPLIT_N, N_NODES - SPLIT_N);
}

// ---------------------------------------------------------------------------
// Fused MLP: one 64-row tile per block, BOTH a-branches (a-loop, restage).
// 469 blocks @ 2 blocks/CU = 0.92 rounds -> minimal tail quantization.
// ---------------------------------------------------------------------------
__global__ __launch_bounds__(256, 2) void mlp_kernel(
    const short* __restrict__ h16, const short* __restrict__ wfrag,
    const float* __restrict__ bias, const float* __restrict__ wout,
    float* __restrict__ out)
{
    __shared__ __align__(16) short ylds[64 * 264];
    const int t = threadIdx.x;
    const int wave = t >> 6, lane = t & 63, q = lane >> 4, c15 = lane & 15;
    const int n0 = blockIdx.x * 64;

    for (int a = 0; a < 2; a++) {
        // stage h tile (bf16) into LDS
#pragma unroll
        for (int j = 0; j < 8; j++) {
            int grp = t + j * 256;
            int r = grp >> 5, c8 = grp & 31;
            shortx8 v = {0, 0, 0, 0, 0, 0, 0, 0};
            if (n0 + r < N_NODES)
                v = *(const shortx8*)&h16[(size_t)(n0 + r) * 256 + c8 * 8];
            *(shortx8*)&ylds[r * 264 + c8 * 8] = v;
        }
        __syncthreads();

        for (int lay = 0; lay < 4; lay++) {
            const bf16x8* wf = (const bf16x8*)(wfrag + (size_t)(a * 4 + lay) * 65536);
            floatx4 acc[4][4];
#pragma unroll
            for (int mt = 0; mt < 4; mt++)
#pragma unroll
                for (int nt = 0; nt < 4; nt++)
                    acc[mt][nt] = (floatx4){0.f, 0.f, 0.f, 0.f};

#pragma unroll
            for (int ks = 0; ks < 8; ks++) {
                bf16x8 bfr[4];
#pragma unroll
                for (int nt = 0; nt < 4; nt++)
                    bfr[nt] = wf[(ks * 16 + wave * 4 + nt) * 64 + lane];
#pragma unroll
                for (int mt = 0; mt < 4; mt++) {
                    bf16x8 afr = *(const bf16x8*)&ylds[(mt * 16 + c15) * 264 + ks * 32 + q * 8];
#pragma unroll
                    for (int nt = 0; nt < 4; nt++)
                        acc[mt][nt] = __builtin_amdgcn_mfma_f32_16x16x32_bf16(
                            afr, bfr[nt], acc[mt][nt], 0, 0, 0);
                }
            }
            __syncthreads();          // all reads done before overwrite

            float bv[4];
#pragma unroll
            for (int nt = 0; nt < 4; nt++)
                bv[nt] = (lay >= 1)
                       ? bias[(a * 3 + lay - 1) * 256 + wave * 64 + nt * 16 + c15]
                       : 0.0f;
#pragma unroll
            for (int mt = 0; mt < 4; mt++)
#pragma unroll
                for (int nt = 0; nt < 4; nt++)
#pragma unroll
                    for (int rg = 0; rg < 4; rg++) {
                        float v = acc[mt][nt][rg] + bv[nt];
                        if (lay >= 1) v = v / (1.0f + __expf(-v));   // SiLU
                        ylds[(mt * 16 + q * 4 + rg) * 264 + wave * 64 + nt * 16 + c15] = f2bf(v);
                    }
            __syncthreads();
        }

        // output projection: y3[64][256] . wout[a][256]
        {
            int r  = wave * 16 + (lane >> 2);
            int cq = lane & 3;
            const float* wo = wout + a * 256 + cq * 64;
            const short* yp = &ylds[r * 264 + cq * 64];
            float s = 0.0f;
#pragma unroll
            for (int bb = 0; bb < 8; bb++) {
                shortx8 v = *(const shortx8*)&yp[bb * 8];
#pragma unroll
                for (int j = 0; j < 8; j++) s += bf2f(v[j]) * wo[bb * 8 + j];
            }
            s += __shfl_xor(s, 1);
            s += __shfl_xor(s, 2);
            if (cq == 0 && n0 + r < N_NODES) out[a * N_NODES + n0 + r] = s;
        }
        __syncthreads();              // ylds reads done before next-a restage
    }
}

// ---------------------------------------------------------------------------
extern "C" void kernel_launch(void* const* d_in, const int* in_sizes, int n_in,
                              void* d_out, int out_size, void* d_ws, size_t ws_size,
                              hipStream_t stream)
{
    (void)in_sizes; (void)n_in; (void)out_size; (void)ws_size;
    const float* x    = (const float*)d_in[0];
    const float* rbf  = (const float*)d_in[1];
    const int*   idx  = (const int*)d_in[2];
    const float* wrbf = (const float*)d_in[4];
    const float* wup  = (const float*)d_in[5];
    const float* whid = (const float*)d_in[6];
    const float* bias = (const float*)d_in[7];
    const float* wout = (const float*)d_in[8];
    float* out = (float*)d_out;

    char* ws = (char*)d_ws;
    short* h16       = (short*)ws;  ws += (size_t)N_NODES * H_DIM * sizeof(short);
    short* wfrag     = (short*)ws;  ws += (size_t)8 * 65536 * sizeof(short);
    int*   counts    = (int*)ws;    ws += (size_t)N_NODES * sizeof(int);
    int*   offsets   = (int*)ws;    ws += (size_t)(N_NODES + 1) * sizeof(int);
    int*   cursor    = (int*)ws;    ws += (size_t)N_NODES * sizeof(int);
    int*   edge_list = (int*)ws;

    hipMemsetAsync(counts, 0, (size_t)N_NODES * sizeof(int), stream);
    prep_hist<<<256 + SCAT_BLOCKS, 256, 0, stream>>>(wup, whid, wfrag, idx, counts);
    scan_kernel<<<1, 1024, 0, stream>>>(counts, offsets, cursor);
    scatter_lo<<<SCAT_BLOCKS, 256, 0, stream>>>(idx, cursor, edge_list);
    scatterB_gatherA<<<SCAT_BLOCKS + SPLIT_N / 4, 256, 0, stream>>>(
        idx, cursor, edge_list, x, rbf, offsets, wrbf, h16);
    gather_hi<<<(N_NODES - SPLIT_N) / 4, 256, 0, stream>>>(
        x, rbf, edge_list, offsets, wrbf, h16);
    mlp_kernel<<<(N_NODES + 63) / 64, 256, 0, stream>>>(h16, wfrag, bias, wout, out);
}